// Round 3
// baseline (797.822 us; speedup 1.0000x reference)
//
#include <hip/hip_runtime.h>
#include <hip/hip_bf16.h>

#define Bb 128
#define Cc 128
#define Dd 256
#define Kk 1024
#define KT 128           // k-tile per k_dist block
#define NT (Kk / KT)     // 8 partial tiles
#define BKd 32           // d-step staged in LDS

#define DEC  0.99f
#define ODEC ((float)(1.0 - 0.99))          // f64 -> f32, matches JAX rounding
#define KEPS ((float)(1024 * 1e-05))        // k*EPS computed in f64, then f32
#define EPSf 1e-5f

// ---------------------------------------------------------------------------
// Kernel A: per (c, k-tile): dist_bk = ||e_k||^2 - 2 * dot(x_b, e_k), fused
// per-b argmin within the tile -> partial (val, idx).
// grid (NT, C), 256 threads, 8x8 microtile fp32 GEMM.
// ---------------------------------------------------------------------------
__global__ __launch_bounds__(256, 2)
void k_dist(const float* __restrict__ z, const float* __restrict__ emb,
            float* __restrict__ pval, int* __restrict__ pidx) {
    const int kt = blockIdx.x;
    const int c  = blockIdx.y;
    const int tid = threadIdx.x;
    const int i = tid >> 4;   // 0..15  (row group: b = i*8..i*8+7)
    const int j = tid & 15;   // 0..15  (col group: k = j*8..j*8+7)

    __shared__ float As[BKd][132];   // [d][b], +4 pad
    __shared__ float Bs[BKd][132];   // [d][k_local]
    __shared__ float e2s[KT];
    __shared__ float rv[Bb][17];
    __shared__ int   ri[Bb][17];

    float acc[8][8];
#pragma unroll
    for (int u = 0; u < 8; ++u)
#pragma unroll
        for (int v = 0; v < 8; ++v) acc[u][v] = 0.f;
    float e2acc = 0.f;

    const float* zc = z   + (size_t)c * Dd;                       // x[c][b][d] = z[b][c][d]
    const float* ec = emb + ((size_t)c * Kk + (size_t)kt * KT) * Dd;

    for (int d0 = 0; d0 < Dd; d0 += BKd) {
        // ---- stage A (x rows) and B (e rows), transposed into LDS ----
#pragma unroll
        for (int n = 0; n < 4; ++n) {
            const int li  = tid + n * 256;        // 0..1023
            const int row = li >> 3;              // 0..127
            const int f4  = li & 7;               // 0..7
            const float4 av = *(const float4*)(zc + (size_t)row * Cc * Dd + d0 + f4 * 4);
            const float4 bv = *(const float4*)(ec + (size_t)row * Dd      + d0 + f4 * 4);
            const int kb = f4 * 4;
            As[kb + 0][row] = av.x; As[kb + 1][row] = av.y;
            As[kb + 2][row] = av.z; As[kb + 3][row] = av.w;
            Bs[kb + 0][row] = bv.x; Bs[kb + 1][row] = bv.y;
            Bs[kb + 2][row] = bv.z; Bs[kb + 3][row] = bv.w;
        }
        __syncthreads();

        // ---- ||e||^2 partial (waves 0-1 only; per-k column sums) ----
        if (tid < KT) {
#pragma unroll
            for (int kk = 0; kk < BKd; ++kk) {
                const float v = Bs[kk][tid];
                e2acc = fmaf(v, v, e2acc);
            }
        }

        // ---- rank-1 updates ----
#pragma unroll
        for (int kk = 0; kk < BKd; ++kk) {
            float a[8], b[8];
            *(float4*)&a[0] = *(const float4*)&As[kk][i * 8];
            *(float4*)&a[4] = *(const float4*)&As[kk][i * 8 + 4];
            *(float4*)&b[0] = *(const float4*)&Bs[kk][j * 8];
            *(float4*)&b[4] = *(const float4*)&Bs[kk][j * 8 + 4];
#pragma unroll
            for (int u = 0; u < 8; ++u)
#pragma unroll
                for (int v = 0; v < 8; ++v)
                    acc[u][v] = fmaf(a[u], b[v], acc[u][v]);
        }
        __syncthreads();
    }

    if (tid < KT) e2s[tid] = e2acc;
    __syncthreads();

    // per-thread min over its 8 columns, per row
    float e2r[8];
#pragma unroll
    for (int v = 0; v < 8; ++v) e2r[v] = e2s[j * 8 + v];
#pragma unroll
    for (int u = 0; u < 8; ++u) {
        float bv = 1e30f; int bi = 0;
#pragma unroll
        for (int v = 0; v < 8; ++v) {
            const float dv = fmaf(-2.f, acc[u][v], e2r[v]);
            if (dv < bv) { bv = dv; bi = j * 8 + v; }   // strict <: first-index tie-break
        }
        rv[i * 8 + u][j] = bv;
        ri[i * 8 + u][j] = bi;
    }
    __syncthreads();

    // reduce across the 16 column groups (ascending j => ascending k, strict <)
    if (tid < Bb) {
        float bv = rv[tid][0]; int bi = ri[tid][0];
#pragma unroll
        for (int jj = 1; jj < 16; ++jj) {
            const float v = rv[tid][jj];
            if (v < bv) { bv = v; bi = ri[tid][jj]; }
        }
        const size_t o = ((size_t)c * Bb + tid) * NT + kt;
        pval[o] = bv;
        pidx[o] = kt * KT + bi;
    }
}

// ---------------------------------------------------------------------------
// Kernel B: merge partials -> index; gather quant row; q_st; commit-loss
// partial; n_i count; indices.T (float). grid B*C, 256 threads (one per d).
// ---------------------------------------------------------------------------
__global__ __launch_bounds__(256)
void k_quant(const float* __restrict__ z, const float* __restrict__ emb,
             const float* __restrict__ pval, const int* __restrict__ pidx,
             float* __restrict__ qst, float* __restrict__ idxf,
             int* __restrict__ widx, float* __restrict__ ni,
             float* __restrict__ loss) {
    const int bid = blockIdx.x;
    const int b = bid / Cc;
    const int c = bid % Cc;
    const int tid = threadIdx.x;

    __shared__ int   sidx_s;
    __shared__ float wsum[4];

    if (tid == 0) {
        const float* pv = pval + ((size_t)c * Bb + b) * NT;
        const int*   pi = pidx + ((size_t)c * Bb + b) * NT;
        float bv = pv[0]; int bi = pi[0];
#pragma unroll
        for (int t = 1; t < NT; ++t) {
            const float v = pv[t];
            if (v < bv) { bv = v; bi = pi[t]; }   // ascending kt, strict <
        }
        sidx_s = bi;
    }
    __syncthreads();
    const int sidx = sidx_s;

    const float q  = emb[((size_t)c * Kk + sidx) * Dd + tid];
    const size_t zo = ((size_t)b * Cc + c) * Dd + tid;
    const float zv = z[zo];
    const float diff = q - zv;
    qst[zo] = zv + diff;                // z + (quantized - z), as the reference computes

    float ls = diff * diff;
#pragma unroll
    for (int o = 32; o > 0; o >>= 1) ls += __shfl_down(ls, o, 64);
    const int w = tid >> 6, lane = tid & 63;
    if (lane == 0) wsum[w] = ls;
    __syncthreads();
    if (tid == 0) {
        atomicAdd(loss, wsum[0] + wsum[1] + wsum[2] + wsum[3]);
        atomicAdd(&ni[(size_t)c * Kk + sidx], 1.0f);
        idxf[(size_t)b * Cc + c] = (float)sidx;   // indices.T is (B, C)
        widx[(size_t)c * Bb + b] = sidx;
    }
}

// ---------------------------------------------------------------------------
// Kernel C: new_cluster_size, n_tot, smoothed denominator; finalize loss.
// grid C, 256 threads (4 k per thread).
// ---------------------------------------------------------------------------
__global__ __launch_bounds__(256)
void k_cluster(const float* __restrict__ ema_cs, const float* __restrict__ ni,
               float* __restrict__ ncs_out, float* __restrict__ sm,
               const float* __restrict__ loss, float* __restrict__ loss_out) {
    const int c = blockIdx.x;
    const int tid = threadIdx.x;
    __shared__ float wsum[4];
    __shared__ float ntot_s;

    float v[4]; float s = 0.f;
#pragma unroll
    for (int q = 0; q < 4; ++q) {
        const int k = tid + q * 256;
        v[q] = fmaf(ODEC, ni[(size_t)c * Kk + k], DEC * ema_cs[(size_t)c * Kk + k]);
        s += v[q];
    }
#pragma unroll
    for (int o = 32; o > 0; o >>= 1) s += __shfl_down(s, o, 64);
    const int w = tid >> 6, lane = tid & 63;
    if (lane == 0) wsum[w] = s;
    __syncthreads();
    if (tid == 0) ntot_s = wsum[0] + wsum[1] + wsum[2] + wsum[3];
    __syncthreads();
    const float ntot = ntot_s;

#pragma unroll
    for (int q = 0; q < 4; ++q) {
        const int k = tid + q * 256;
        ncs_out[(size_t)c * Kk + k] = v[q];
        sm[(size_t)c * Kk + k] = (v[q] + EPSf) / (ntot + KEPS) * ntot;
    }
    if (c == 0 && tid == 0)
        loss_out[0] = 0.25f * loss[0] / (float)((size_t)Bb * Cc * Dd);
}

// ---------------------------------------------------------------------------
// Kernel D: e_i gather via ballot + EMA update + normalized embedding.
// grid (K/4, C), 256 threads = 4 waves, one wave per k. float4 per lane (d).
// ---------------------------------------------------------------------------
__global__ __launch_bounds__(256)
void k_ema(const float* __restrict__ z, const float* __restrict__ ema_es,
           const int* __restrict__ widx, const float* __restrict__ sm,
           float* __restrict__ nes_out, float* __restrict__ nemb_out) {
    const int c = blockIdx.y;
    const int w = threadIdx.x >> 6;
    const int lane = threadIdx.x & 63;
    const int k = blockIdx.x * 4 + w;

    const int i0 = widx[(size_t)c * Bb + lane];
    const int i1 = widx[(size_t)c * Bb + 64 + lane];
    unsigned long long m0 = __ballot(i0 == k);
    unsigned long long m1 = __ballot(i1 == k);

    float ax = 0.f, ay = 0.f, az = 0.f, aw = 0.f;
    const float* zc = z + (size_t)c * Dd + lane * 4;
    while (m0) {   // wave-uniform mask -> uniform loop, ascending b
        const int b = __builtin_ctzll(m0); m0 &= m0 - 1;
        const float4 xv = *(const float4*)(zc + (size_t)b * Cc * Dd);
        ax += xv.x; ay += xv.y; az += xv.z; aw += xv.w;
    }
    while (m1) {
        const int b = 64 + __builtin_ctzll(m1); m1 &= m1 - 1;
        const float4 xv = *(const float4*)(zc + (size_t)b * Cc * Dd);
        ax += xv.x; ay += xv.y; az += xv.z; aw += xv.w;
    }

    const size_t off = ((size_t)c * Kk + k) * Dd + lane * 4;
    const float4 ev = *(const float4*)(ema_es + off);
    const float smv = sm[(size_t)c * Kk + k];

    float4 nes;
    nes.x = fmaf(ODEC, ax, DEC * ev.x);
    nes.y = fmaf(ODEC, ay, DEC * ev.y);
    nes.z = fmaf(ODEC, az, DEC * ev.z);
    nes.w = fmaf(ODEC, aw, DEC * ev.w);
    *(float4*)(nes_out + off) = nes;

    float4 ne;
    ne.x = nes.x / smv; ne.y = nes.y / smv;
    ne.z = nes.z / smv; ne.w = nes.w / smv;
    *(float4*)(nemb_out + off) = ne;
}

// ---------------------------------------------------------------------------
extern "C" void kernel_launch(void* const* d_in, const int* in_sizes, int n_in,
                              void* d_out, int out_size, void* d_ws, size_t ws_size,
                              hipStream_t stream) {
    const float* z      = (const float*)d_in[0];   // (B,C,H,W)
    const float* emb    = (const float*)d_in[1];   // (C,K,D)
    const float* ema_cs = (const float*)d_in[2];   // (C,K)
    const float* ema_es = (const float*)d_in[3];   // (C,K,D)

    float* out = (float*)d_out;
    // output layout (flat, return order):
    float* o_qst  = out;                           //  4,194,304
    float* o_loss = out + 4194304;                 //  1
    float* o_idx  = out + 4194305;                 //  16,384   (indices.T as float)
    float* o_emb  = out + 4210689;                 //  33,554,432
    float* o_ncs  = out + 37765121;                //  131,072
    float* o_nes  = out + 37896193;                //  33,554,432

    // scratch: n_i / loss / widx / smoothed live in ws (~1.1 MB);
    // argmin partials are stashed in the o_nes output region (read by k_quant
    // before k_ema overwrites it).
    float* ws   = (float*)d_ws;
    float* ni   = ws;                              // 131,072 floats
    float* loss = ws + 131072;                     // 1 float
    int*   widx = (int*)(ws + 131104);             // 16,384 ints
    float* sm   = ws + 147488;                     // 131,072 floats
    float* pval = o_nes;                           // C*B*NT = 131,072 floats
    int*   pidx = (int*)(o_nes + 131072);          // 131,072 ints

    hipMemsetAsync(ni, 0, (size_t)(131072 + 1) * sizeof(float), stream);

    k_dist   <<<dim3(NT, Cc), 256, 0, stream>>>(z, emb, pval, pidx);
    k_quant  <<<Bb * Cc,      256, 0, stream>>>(z, emb, pval, pidx,
                                                o_qst, o_idx, widx, ni, loss);
    k_cluster<<<Cc,           256, 0, stream>>>(ema_cs, ni, o_ncs, sm, loss, o_loss);
    k_ema    <<<dim3(Kk / 4, Cc), 256, 0, stream>>>(z, ema_es, widx, sm, o_nes, o_emb);
}

// Round 5
// 594.057 us; speedup vs baseline: 1.3430x; 1.3430x over previous
//
#include <hip/hip_runtime.h>
#include <hip/hip_bf16.h>

#define Bb 128
#define Cc 128
#define Dd 256
#define Kk 1024
#define KT 128           // k-tile per k_dist block
#define NT (Kk / KT)     // 8 partial tiles
#define BKd 32           // d-step staged in LDS

#define DEC  0.99f
#define ODEC ((float)(1.0 - 0.99))          // f64 -> f32, matches JAX rounding
#define KEPS ((float)(1024 * 1e-05))        // k*EPS computed in f64, then f32
#define EPSf 1e-5f

// ---------------------------------------------------------------------------
// Kernel A: per (c, k-tile): dist_bk = ||e_k||^2 - 2 * dot(x_b, e_k), fused
// per-b argmin within the tile -> partial (val, idx). grid (NT, C), 256 thr.
// ---------------------------------------------------------------------------
__global__ __launch_bounds__(256, 2)
void k_dist(const float* __restrict__ z, const float* __restrict__ emb,
            float* __restrict__ pval, int* __restrict__ pidx) {
    const int kt = blockIdx.x;
    const int c  = blockIdx.y;
    const int tid = threadIdx.x;
    const int i = tid >> 4;   // 0..15  (row group: b = i*8..i*8+7)
    const int j = tid & 15;   // 0..15  (col group: k = j*8..j*8+7)

    __shared__ float As[BKd][132];   // [d][b], +4 pad
    __shared__ float Bs[BKd][132];   // [d][k_local]
    __shared__ float e2s[KT];
    __shared__ float rv[Bb][17];
    __shared__ int   ri[Bb][17];

    float acc[8][8];
#pragma unroll
    for (int u = 0; u < 8; ++u)
#pragma unroll
        for (int v = 0; v < 8; ++v) acc[u][v] = 0.f;
    float e2acc = 0.f;

    const float* zc = z   + (size_t)c * Dd;                       // x[c][b][d] = z[b][c][d]
    const float* ec = emb + ((size_t)c * Kk + (size_t)kt * KT) * Dd;

    for (int d0 = 0; d0 < Dd; d0 += BKd) {
#pragma unroll
        for (int n = 0; n < 4; ++n) {
            const int li  = tid + n * 256;        // 0..1023
            const int row = li >> 3;              // 0..127
            const int f4  = li & 7;               // 0..7
            const float4 av = *(const float4*)(zc + (size_t)row * Cc * Dd + d0 + f4 * 4);
            const float4 bv = *(const float4*)(ec + (size_t)row * Dd      + d0 + f4 * 4);
            const int kb = f4 * 4;
            As[kb + 0][row] = av.x; As[kb + 1][row] = av.y;
            As[kb + 2][row] = av.z; As[kb + 3][row] = av.w;
            Bs[kb + 0][row] = bv.x; Bs[kb + 1][row] = bv.y;
            Bs[kb + 2][row] = bv.z; Bs[kb + 3][row] = bv.w;
        }
        __syncthreads();

        if (tid < KT) {
#pragma unroll
            for (int kk = 0; kk < BKd; ++kk) {
                const float v = Bs[kk][tid];
                e2acc = fmaf(v, v, e2acc);
            }
        }

#pragma unroll
        for (int kk = 0; kk < BKd; ++kk) {
            float a[8], b[8];
            *(float4*)&a[0] = *(const float4*)&As[kk][i * 8];
            *(float4*)&a[4] = *(const float4*)&As[kk][i * 8 + 4];
            *(float4*)&b[0] = *(const float4*)&Bs[kk][j * 8];
            *(float4*)&b[4] = *(const float4*)&Bs[kk][j * 8 + 4];
#pragma unroll
            for (int u = 0; u < 8; ++u)
#pragma unroll
                for (int v = 0; v < 8; ++v)
                    acc[u][v] = fmaf(a[u], b[v], acc[u][v]);
        }
        __syncthreads();
    }

    if (tid < KT) e2s[tid] = e2acc;
    __syncthreads();

    float e2r[8];
#pragma unroll
    for (int v = 0; v < 8; ++v) e2r[v] = e2s[j * 8 + v];
#pragma unroll
    for (int u = 0; u < 8; ++u) {
        float bv = 1e30f; int bi = 0;
#pragma unroll
        for (int v = 0; v < 8; ++v) {
            const float dv = fmaf(-2.f, acc[u][v], e2r[v]);
            if (dv < bv) { bv = dv; bi = j * 8 + v; }   // strict <: first-index tie-break
        }
        rv[i * 8 + u][j] = bv;
        ri[i * 8 + u][j] = bi;
    }
    __syncthreads();

    if (tid < Bb) {
        float bv = rv[tid][0]; int bi = ri[tid][0];
#pragma unroll
        for (int jj = 1; jj < 16; ++jj) {
            const float v = rv[tid][jj];
            if (v < bv) { bv = v; bi = ri[tid][jj]; }
        }
        const size_t o = ((size_t)c * Bb + tid) * NT + kt;
        pval[o] = bv;
        pidx[o] = kt * KT + bi;
    }
}

// ---------------------------------------------------------------------------
// Kernel A2: merge NT partials per (c,b) -> widx, idxf. 64 blocks x 256 thr.
// ---------------------------------------------------------------------------
__global__ __launch_bounds__(256)
void k_argmin(const float* __restrict__ pval, const int* __restrict__ pidx,
              int* __restrict__ widx, float* __restrict__ idxf) {
    const int t = blockIdx.x * 256 + threadIdx.x;   // t = c*Bb + b
    const int c = t >> 7, b = t & 127;
    const float* pv = pval + (size_t)t * NT;
    const int*   pi = pidx + (size_t)t * NT;
    float bv = pv[0]; int bi = pi[0];
#pragma unroll
    for (int q = 1; q < NT; ++q) {       // ascending kt, strict <
        const float v = pv[q];
        if (v < bv) { bv = v; bi = pi[q]; }
    }
    widx[t] = bi;
    idxf[(size_t)b * Cc + c] = (float)bi;   // indices.T is (B, C)
}

// ---------------------------------------------------------------------------
// Kernel B: gather quant row + q_st + per-block loss partial (NO atomics).
// 1024 blocks x 256 threads, 16 (b,c) rows per block, float4 everywhere.
// ---------------------------------------------------------------------------
__global__ __launch_bounds__(256)
void k_quant(const float* __restrict__ z, const float* __restrict__ emb,
             const int* __restrict__ widx,
             float* __restrict__ qst, float* __restrict__ lossbuf) {
    const int tid = threadIdx.x;
    const int row0 = blockIdx.x * 16;
    __shared__ int   sidx_s[16];
    __shared__ float wsum[4];

    if (tid < 16) {
        const int r = row0 + tid;        // r = b*Cc + c
        const int b = r >> 7, c = r & 127;
        sidx_s[tid] = widx[c * Bb + b];
    }
    __syncthreads();

    const int rr = tid >> 4;             // 0..15 (row within block)
    const int f0 = tid & 15;             // 0..15 (float4 lane group)
    const int r  = row0 + rr;
    const int c  = r & 127;
    const int sidx = sidx_s[rr];
    const float4* zr = (const float4*)(z   + (size_t)r * Dd);
    const float4* er = (const float4*)(emb + ((size_t)c * Kk + sidx) * Dd);
    float4* qr = (float4*)(qst + (size_t)r * Dd);

    float ls = 0.f;
#pragma unroll
    for (int q = 0; q < 4; ++q) {
        const int f = f0 + q * 16;
        const float4 zv = zr[f];
        const float4 ev = er[f];
        const float dx = ev.x - zv.x, dy = ev.y - zv.y;
        const float dz = ev.z - zv.z, dw = ev.w - zv.w;
        float4 o;                        // z + (quant - z), as the reference computes
        o.x = zv.x + dx; o.y = zv.y + dy; o.z = zv.z + dz; o.w = zv.w + dw;
        qr[f] = o;
        ls += dx * dx + dy * dy + dz * dz + dw * dw;
    }
#pragma unroll
    for (int o = 32; o > 0; o >>= 1) ls += __shfl_down(ls, o, 64);
    const int w = tid >> 6, lane = tid & 63;
    if (lane == 0) wsum[w] = ls;
    __syncthreads();
    if (tid == 0) lossbuf[blockIdx.x] = wsum[0] + wsum[1] + wsum[2] + wsum[3];
}

// ---------------------------------------------------------------------------
// Kernel C: n_i from widx (LDS broadcast count), new_cluster_size, n_tot,
// smoothed; block c==0 also reduces the 1024 loss partials. grid C, 256 thr.
// ---------------------------------------------------------------------------
__global__ __launch_bounds__(256)
void k_cluster(const float* __restrict__ ema_cs, const int* __restrict__ widx,
               const float* __restrict__ lossbuf,
               float* __restrict__ ncs_out, float* __restrict__ sm,
               float* __restrict__ loss_out) {
    const int c = blockIdx.x;
    const int tid = threadIdx.x;
    __shared__ int   swidx[Bb];
    __shared__ float wsum[4];
    __shared__ float ntot_s;

    if (tid < Bb) swidx[tid] = widx[c * Bb + tid];
    __syncthreads();

    float v[4]; float s = 0.f;
#pragma unroll
    for (int q = 0; q < 4; ++q) {
        const int k = tid + q * 256;
        int cnt = 0;
#pragma unroll 16
        for (int b = 0; b < Bb; ++b) cnt += (swidx[b] == k) ? 1 : 0;
        v[q] = fmaf(ODEC, (float)cnt, DEC * ema_cs[(size_t)c * Kk + k]);
        s += v[q];
    }
#pragma unroll
    for (int o = 32; o > 0; o >>= 1) s += __shfl_down(s, o, 64);
    const int w = tid >> 6, lane = tid & 63;
    if (lane == 0) wsum[w] = s;
    __syncthreads();
    if (tid == 0) ntot_s = wsum[0] + wsum[1] + wsum[2] + wsum[3];
    __syncthreads();
    const float ntot = ntot_s;

#pragma unroll
    for (int q = 0; q < 4; ++q) {
        const int k = tid + q * 256;
        ncs_out[(size_t)c * Kk + k] = v[q];
        sm[(size_t)c * Kk + k] = (v[q] + EPSf) / (ntot + KEPS) * ntot;
    }

    if (c == 0) {   // reduce loss partials (block-uniform branch)
        float s2 = 0.f;
#pragma unroll
        for (int q = 0; q < 4; ++q) s2 += lossbuf[tid + q * 256];
#pragma unroll
        for (int o = 32; o > 0; o >>= 1) s2 += __shfl_down(s2, o, 64);
        __syncthreads();                 // wsum reuse
        if (lane == 0) wsum[w] = s2;
        __syncthreads();
        if (tid == 0)
            loss_out[0] = 0.25f * (wsum[0] + wsum[1] + wsum[2] + wsum[3]) / 4194304.0f;
    }
}

// ---------------------------------------------------------------------------
// Kernel D: e_i gather via ballot + EMA update + normalized embedding.
// grid (K/4, C), 256 threads = 4 waves, one wave per k. float4 per lane (d).
// ---------------------------------------------------------------------------
__global__ __launch_bounds__(256)
void k_ema(const float* __restrict__ z, const float* __restrict__ ema_es,
           const int* __restrict__ widx, const float* __restrict__ sm,
           float* __restrict__ nes_out, float* __restrict__ nemb_out) {
    const int c = blockIdx.y;
    const int w = threadIdx.x >> 6;
    const int lane = threadIdx.x & 63;
    const int k = blockIdx.x * 4 + w;

    const int i0 = widx[(size_t)c * Bb + lane];
    const int i1 = widx[(size_t)c * Bb + 64 + lane];
    unsigned long long m0 = __ballot(i0 == k);
    unsigned long long m1 = __ballot(i1 == k);

    float ax = 0.f, ay = 0.f, az = 0.f, aw = 0.f;
    const float* zc = z + (size_t)c * Dd + lane * 4;
    while (m0) {   // wave-uniform mask -> uniform loop, ascending b
        const int b = __builtin_ctzll(m0); m0 &= m0 - 1;
        const float4 xv = *(const float4*)(zc + (size_t)b * Cc * Dd);
        ax += xv.x; ay += xv.y; az += xv.z; aw += xv.w;
    }
    while (m1) {
        const int b = 64 + __builtin_ctzll(m1); m1 &= m1 - 1;
        const float4 xv = *(const float4*)(zc + (size_t)b * Cc * Dd);
        ax += xv.x; ay += xv.y; az += xv.z; aw += xv.w;
    }

    const size_t off = ((size_t)c * Kk + k) * Dd + lane * 4;
    const float4 ev = *(const float4*)(ema_es + off);
    const float smv = sm[(size_t)c * Kk + k];

    float4 nes;
    nes.x = fmaf(ODEC, ax, DEC * ev.x);
    nes.y = fmaf(ODEC, ay, DEC * ev.y);
    nes.z = fmaf(ODEC, az, DEC * ev.z);
    nes.w = fmaf(ODEC, aw, DEC * ev.w);
    *(float4*)(nes_out + off) = nes;

    float4 ne;
    ne.x = nes.x / smv; ne.y = nes.y / smv;
    ne.z = nes.z / smv; ne.w = nes.w / smv;
    *(float4*)(nemb_out + off) = ne;
}

// ---------------------------------------------------------------------------
extern "C" void kernel_launch(void* const* d_in, const int* in_sizes, int n_in,
                              void* d_out, int out_size, void* d_ws, size_t ws_size,
                              hipStream_t stream) {
    const float* z      = (const float*)d_in[0];   // (B,C,H,W)
    const float* emb    = (const float*)d_in[1];   // (C,K,D)
    const float* ema_cs = (const float*)d_in[2];   // (C,K)
    const float* ema_es = (const float*)d_in[3];   // (C,K,D)

    float* out = (float*)d_out;
    float* o_qst  = out;                           //  4,194,304
    float* o_loss = out + 4194304;                 //  1
    float* o_idx  = out + 4194305;                 //  16,384
    float* o_emb  = out + 4210689;                 //  33,554,432
    float* o_ncs  = out + 37765121;                //  131,072
    float* o_nes  = out + 37896193;                //  33,554,432

    // scratch (~0.6 MB): widx / sm / lossbuf. argmin partials stashed in the
    // o_nes output region (read by k_argmin, overwritten later by k_ema).
    float* ws      = (float*)d_ws;
    int*   widx    = (int*)ws;                     // 16,384 ints
    float* sm      = ws + 16384;                   // 131,072 floats
    float* lossbuf = ws + 16384 + 131072;          // 1,024 floats
    float* pval    = o_nes;                        // C*B*NT = 131,072 floats
    int*   pidx    = (int*)(o_nes + 131072);       // 131,072 ints

    k_dist   <<<dim3(NT, Cc), 256, 0, stream>>>(z, emb, pval, pidx);
    k_argmin <<<Bb * Cc / 256, 256, 0, stream>>>(pval, pidx, widx, o_idx);
    k_quant  <<<Bb * Cc / 16,  256, 0, stream>>>(z, emb, widx, o_qst, lossbuf);
    k_cluster<<<Cc,            256, 0, stream>>>(ema_cs, widx, lossbuf,
                                                 o_ncs, sm, o_loss);
    k_ema    <<<dim3(Kk / 4, Cc), 256, 0, stream>>>(z, ema_es, widx, sm, o_nes, o_emb);
}